// Round 1
// baseline (137.302 us; speedup 1.0000x reference)
//
#include <hip/hip_runtime.h>
#include <stdint.h>

#define IN_F 4096
#define OUT_F 4096
#define M_ROWS 4096   // B*S = 2*2048
#define BM 128
#define BN 128
#define BK 64

typedef __attribute__((ext_vector_type(8))) short bf16x8;
typedef __attribute__((ext_vector_type(4))) float f32x4;
typedef __attribute__((ext_vector_type(4))) float f4;
typedef __attribute__((ext_vector_type(8))) unsigned short u16x8;

__device__ __forceinline__ unsigned short f32_to_bf16_rne(float f) {
    uint32_t u = __float_as_uint(f);
    u += 0x7FFFu + ((u >> 16) & 1u);
    return (unsigned short)(u >> 16);
}

// ---- prepass 1: x fp32 -> bf16 (8 elems/thread, exact grid) ----
__global__ __launch_bounds__(256) void cvt_x_kernel(const float* __restrict__ x,
                                                    unsigned short* __restrict__ xb) {
    size_t g = (size_t)blockIdx.x * 256 + threadIdx.x;   // one per 8 elements
    const f4* xp = (const f4*)x + g * 2;
    f4 a = xp[0], b = xp[1];
    u16x8 r;
    r[0] = f32_to_bf16_rne(a[0]); r[1] = f32_to_bf16_rne(a[1]);
    r[2] = f32_to_bf16_rne(a[2]); r[3] = f32_to_bf16_rne(a[3]);
    r[4] = f32_to_bf16_rne(b[0]); r[5] = f32_to_bf16_rne(b[1]);
    r[6] = f32_to_bf16_rne(b[2]); r[7] = f32_to_bf16_rne(b[3]);
    *((u16x8*)xb + g) = r;
}

// ---- prepass 2: packed triangular weight -> dense bf16 W[OUT_F][IN_F] ----
__global__ __launch_bounds__(256) void build_w_kernel(const float* __restrict__ wsrc,
                                                      unsigned short* __restrict__ wb) {
    size_t g = (size_t)blockIdx.x * 256 + threadIdx.x;   // one per 8 dense elems
    int o  = (int)(g >> 9);            // IN_F/8 = 512 groups per row
    int i0 = ((int)g & 511) << 3;
    int off = o * IN_F - ((o * (o - 1)) >> 1);   // start of row o in packed weight
    u16x8 r;
#pragma unroll
    for (int j = 0; j < 8; ++j) {
        int i = i0 + j;
        float v = (i >= o) ? wsrc[off + (i - o)] : 0.0f;
        r[j] = f32_to_bf16_rne(v);
    }
    *((u16x8*)wb + g) = r;
}

// ---- main GEMM: C[m][n] = sum_{k>=n_tile} A[m][k]*W[n][k] + bias[n] ----
__global__ __launch_bounds__(256, 2) void tri_gemm_kernel(const unsigned short* __restrict__ A,
                                                          const unsigned short* __restrict__ W,
                                                          const float* __restrict__ bias,
                                                          float* __restrict__ C) {
    __shared__ unsigned short As[BM * BK];   // 16 KiB
    __shared__ unsigned short Bs[BN * BK];   // 16 KiB

    const int u = blockIdx.x;
    const int tile_n = u >> 5;    // longest-K tiles dispatched first (LPT balance)
    const int tile_m = u & 31;
    const int m_base = tile_m * BM;
    const int n_base = tile_n * BN;

    const int tid  = threadIdx.x;
    const int wid  = tid >> 6;
    const int lane = tid & 63;
    const int wr = wid >> 1, wc = wid & 1;

    // staging decomposition: lane -> (row within 8-row group, 16B k-chunk)
    const int lrow = lane >> 3;          // 0..7
    const int lk   = (lane & 7) * 8;     // k element offset, 16B granules

    // fragment addressing (16x16x32 bf16): row = lane&15, k = (lane>>4)*8
    const int frow = lane & 15;
    const int fk   = (lane >> 4) * 8;

    f32x4 acc[4][4];
#pragma unroll
    for (int i = 0; i < 4; ++i)
#pragma unroll
        for (int j = 0; j < 4; ++j) acc[i][j] = (f32x4){0.f, 0.f, 0.f, 0.f};

    for (int k0 = n_base; k0 < IN_F; k0 += BK) {
        // ---- stage A-tile and W-tile via async global->LDS, 16B/lane ----
#pragma unroll
        for (int j = 0; j < 4; ++j) {
            const int rs = j * 32 + wid * 8;     // wave-uniform row start (8 rows/wave/issue)
            const unsigned short* ga = A + (size_t)(m_base + rs + lrow) * IN_F + k0 + lk;
            __builtin_amdgcn_global_load_lds(
                (const __attribute__((address_space(1))) void*)ga,
                (__attribute__((address_space(3))) void*)(As + rs * BK), 16, 0, 0);
            const unsigned short* gw = W + (size_t)(n_base + rs + lrow) * IN_F + k0 + lk;
            __builtin_amdgcn_global_load_lds(
                (const __attribute__((address_space(1))) void*)gw,
                (__attribute__((address_space(3))) void*)(Bs + rs * BK), 16, 0, 0);
        }
        __syncthreads();   // compiler drains vmcnt(0) before barrier

        // ---- compute: 2 k-subtiles x 4x4 fragments = 32 MFMA ----
#pragma unroll
        for (int kk = 0; kk < BK; kk += 32) {
            bf16x8 af[4], bfr[4];
#pragma unroll
            for (int i = 0; i < 4; ++i)
                af[i] = *(const bf16x8*)(As + (wr * 64 + i * 16 + frow) * BK + kk + fk);
#pragma unroll
            for (int j = 0; j < 4; ++j)
                bfr[j] = *(const bf16x8*)(Bs + (wc * 64 + j * 16 + frow) * BK + kk + fk);
#pragma unroll
            for (int i = 0; i < 4; ++i)
#pragma unroll
                for (int j = 0; j < 4; ++j)
                    acc[i][j] = __builtin_amdgcn_mfma_f32_16x16x32_bf16(af[i], bfr[j], acc[i][j], 0, 0, 0);
        }
        __syncthreads();
    }

    // ---- epilogue: D layout col=lane&15, row=(lane>>4)*4+q ----
    const int col0 = n_base + wc * 64;
    const int row0 = m_base + wr * 64;
#pragma unroll
    for (int j = 0; j < 4; ++j) {
        const int col = col0 + j * 16 + frow;
        const float bv = bias[col];
#pragma unroll
        for (int i = 0; i < 4; ++i) {
            const int rbase = row0 + i * 16 + (lane >> 4) * 4;
#pragma unroll
            for (int q = 0; q < 4; ++q) {
                C[(size_t)(rbase + q) * OUT_F + col] = acc[i][j][q] + bv;
            }
        }
    }
}

extern "C" void kernel_launch(void* const* d_in, const int* in_sizes, int n_in,
                              void* d_out, int out_size, void* d_ws, size_t ws_size,
                              hipStream_t stream) {
    const float* x    = (const float*)d_in[0];
    const float* w    = (const float*)d_in[1];
    const float* bias = (const float*)d_in[2];
    float* out = (float*)d_out;

    unsigned short* xb = (unsigned short*)d_ws;                  // 32 MiB bf16 x
    unsigned short* wb = xb + (size_t)M_ROWS * IN_F;             // 32 MiB bf16 dense W

    cvt_x_kernel<<<(M_ROWS * IN_F / 8) / 256, 256, 0, stream>>>(x, xb);
    build_w_kernel<<<(OUT_F * IN_F / 8) / 256, 256, 0, stream>>>(w, wb);
    tri_gemm_kernel<<<(M_ROWS / BM) * (OUT_F / BN), 256, 0, stream>>>(xb, wb, bias, out);
}

// Round 2
// 116.330 us; speedup vs baseline: 1.1803x; 1.1803x over previous
//
#include <hip/hip_runtime.h>
#include <stdint.h>

#define IN_F 4096
#define OUT_F 4096
#define M_ROWS 4096   // B*S
#define BM 256
#define BN 128
#define BK 64
#define N_TILES_N 32  // OUT_F/BN
#define N_TILES_M 16  // M_ROWS/BM

typedef __attribute__((ext_vector_type(8))) short bf16x8;
typedef __attribute__((ext_vector_type(4))) float f32x4;
typedef __attribute__((ext_vector_type(4))) float f4;
typedef __attribute__((ext_vector_type(8))) unsigned short u16x8;

__device__ __forceinline__ unsigned short f32_to_bf16_rne(float f) {
    uint32_t u = __float_as_uint(f);
    u += 0x7FFFu + ((u >> 16) & 1u);
    return (unsigned short)(u >> 16);
}

// ---- merged prepass: x fp32->bf16 (blocks [0,8192)), W expand (blocks [8192,16384)) ----
__global__ __launch_bounds__(256) void prep_kernel(const float* __restrict__ x,
                                                   const float* __restrict__ wsrc,
                                                   unsigned short* __restrict__ xb,
                                                   unsigned short* __restrict__ wb) {
    int b = blockIdx.x;
    if (b < 8192) {
        size_t g = (size_t)b * 256 + threadIdx.x;   // one per 8 elems
        const f4* xp = (const f4*)x + g * 2;
        f4 a = xp[0], c = xp[1];
        u16x8 r;
        r[0] = f32_to_bf16_rne(a[0]); r[1] = f32_to_bf16_rne(a[1]);
        r[2] = f32_to_bf16_rne(a[2]); r[3] = f32_to_bf16_rne(a[3]);
        r[4] = f32_to_bf16_rne(c[0]); r[5] = f32_to_bf16_rne(c[1]);
        r[6] = f32_to_bf16_rne(c[2]); r[7] = f32_to_bf16_rne(c[3]);
        *((u16x8*)xb + g) = r;
    } else {
        size_t g = (size_t)(b - 8192) * 256 + threadIdx.x;
        int o  = (int)(g >> 9);
        int i0 = ((int)g & 511) << 3;
        int off = o * IN_F - ((o * (o - 1)) >> 1);
        u16x8 r;
#pragma unroll
        for (int j = 0; j < 8; ++j) {
            int i = i0 + j;
            float v = (i >= o) ? wsrc[off + (i - o)] : 0.0f;
            r[j] = f32_to_bf16_rne(v);
        }
        *((u16x8*)wb + g) = r;
    }
}

// ---- staging: one K-tile (A 256x64 + B 128x64 bf16) into LDS buffers, 6 gload_lds/wave ----
// LDS layout linear [row][slot(16B)x8]; global source col pre-swizzled: gslot = slot ^ (row&7)
__device__ __forceinline__ void stage_tile(const unsigned short* __restrict__ A,
                                           const unsigned short* __restrict__ W,
                                           char* bufA, char* bufB,
                                           int m_base, int n_base, int k0,
                                           int wid, int lane) {
    const int lrow  = lane >> 3;                 // 0..7 (== row&7 of the written row)
    const int gslot = (lane & 7) ^ lrow;         // pre-swizzled source slot
    const size_t coff = (size_t)k0 + (size_t)(gslot << 3);
#pragma unroll
    for (int q = 0; q < 4; ++q) {                // A: 32 rows per wave
        const int rb = q * 64 + wid * 8;
        const unsigned short* g = A + (size_t)(m_base + rb + lrow) * IN_F + coff;
        __builtin_amdgcn_global_load_lds(
            (const __attribute__((address_space(1))) void*)g,
            (__attribute__((address_space(3))) void*)(bufA + rb * 128), 16, 0, 0);
    }
#pragma unroll
    for (int q = 0; q < 2; ++q) {                // B: 16 rows per wave
        const int rb = q * 64 + wid * 8;
        const unsigned short* g = W + (size_t)(n_base + rb + lrow) * IN_F + coff;
        __builtin_amdgcn_global_load_lds(
            (const __attribute__((address_space(1))) void*)g,
            (__attribute__((address_space(3))) void*)(bufB + rb * 128), 16, 0, 0);
    }
}

// ---- main GEMM: C[m][n] = sum_{k>=n_base} A[m][k]*W[n][k] + bias[n] ----
__global__ __launch_bounds__(512, 2) void tri_gemm_kernel(const unsigned short* __restrict__ A,
                                                          const unsigned short* __restrict__ W,
                                                          const float* __restrict__ bias,
                                                          float* __restrict__ C) {
    __shared__ __align__(16) char smem[3 * 49152];   // 3 x (A 32KB + B 16KB) = 144 KiB

    const int u = blockIdx.x;
    const int tile_n = u >> 4;          // longest-K jobs first (greedy LPT balance)
    const int tile_m = u & 15;
    const int m_base = tile_m * BM;
    const int n_base = tile_n * BN;
    const int nt = (IN_F - n_base) / BK;   // >= 2

    const int tid  = threadIdx.x;
    const int wid  = tid >> 6;
    const int lane = tid & 63;
    const int wr = wid >> 1;            // 0..3  (64-row band)
    const int wc = wid & 1;             // 0..1  (64-col band)
    const int frow = lane & 15;
    const int khalf = lane >> 4;        // 0..3 -> k slot offset

    char* pA0 = smem;               char* pB0 = smem + 32768;
    char* pA1 = smem + 49152;       char* pB1 = smem + 49152 + 32768;
    char* pA2 = smem + 2 * 49152;   char* pB2 = smem + 2 * 49152 + 32768;

    f32x4 acc[4][4];
#pragma unroll
    for (int i = 0; i < 4; ++i)
#pragma unroll
        for (int j = 0; j < 4; ++j) acc[i][j] = (f32x4){0.f, 0.f, 0.f, 0.f};

    // prologue: tiles 0 and 1 in flight (6 loads each per wave)
    stage_tile(A, W, pA0, pB0, m_base, n_base, n_base,      wid, lane);
    stage_tile(A, W, pA1, pB1, m_base, n_base, n_base + BK, wid, lane);

    for (int t = 0; t < nt; ++t) {
        if (t + 1 < nt) { asm volatile("s_waitcnt vmcnt(6)" ::: "memory"); }
        else            { asm volatile("s_waitcnt vmcnt(0)" ::: "memory"); }
        __builtin_amdgcn_sched_barrier(0);
        __builtin_amdgcn_s_barrier();   // tile t fully staged; all waves done with buf of t-1
        __builtin_amdgcn_sched_barrier(0);

        if (t + 2 < nt)                 // prefetch t+2 into the buffer freed by t-1
            stage_tile(A, W, pA2, pB2, m_base, n_base, n_base + (t + 2) * BK, wid, lane);

        // ---- compute tile t from pA0/pB0: 16 ds_read_b128 + 32 MFMA ----
        bf16x8 af[2][4], bfr[2][4];
#pragma unroll
        for (int ks = 0; ks < 2; ++ks) {
            const int sbase = (ks << 2) + khalf;          // k-slot 0..7
            const int slot  = sbase ^ (frow & 7);         // XOR bank swizzle
#pragma unroll
            for (int i = 0; i < 4; ++i) {
                const int row = wr * 64 + i * 16 + frow;
                af[ks][i] = *(const bf16x8*)(pA0 + row * 128 + slot * 16);
            }
#pragma unroll
            for (int j = 0; j < 4; ++j) {
                const int row = wc * 64 + j * 16 + frow;
                bfr[ks][j] = *(const bf16x8*)(pB0 + row * 128 + slot * 16);
            }
        }
        __builtin_amdgcn_s_setprio(1);
#pragma unroll
        for (int ks = 0; ks < 2; ++ks)
#pragma unroll
            for (int i = 0; i < 4; ++i)
#pragma unroll
                for (int j = 0; j < 4; ++j)
                    acc[i][j] = __builtin_amdgcn_mfma_f32_16x16x32_bf16(af[ks][i], bfr[ks][j], acc[i][j], 0, 0, 0);
        __builtin_amdgcn_s_setprio(0);

        asm volatile("s_waitcnt lgkmcnt(0)" ::: "memory");   // reads retired before next overwrite window
        __builtin_amdgcn_sched_barrier(0);

        // rotate buffers: t+1 becomes current, freed slot becomes issue target
        char* ta = pA0; pA0 = pA1; pA1 = pA2; pA2 = ta;
        char* tb = pB0; pB0 = pB1; pB1 = pB2; pB2 = tb;
    }

    // ---- epilogue: D layout col=lane&15, row=(lane>>4)*4+q ----
    const int col0 = n_base + wc * 64;
    const int row0 = m_base + wr * 64;
#pragma unroll
    for (int j = 0; j < 4; ++j) {
        const int col = col0 + j * 16 + frow;
        const float bv = bias[col];
#pragma unroll
        for (int i = 0; i < 4; ++i) {
            const int rbase = row0 + i * 16 + khalf * 4;
#pragma unroll
            for (int q = 0; q < 4; ++q) {
                C[(size_t)(rbase + q) * OUT_F + col] = acc[i][j][q] + bv;
            }
        }
    }
}

extern "C" void kernel_launch(void* const* d_in, const int* in_sizes, int n_in,
                              void* d_out, int out_size, void* d_ws, size_t ws_size,
                              hipStream_t stream) {
    const float* x    = (const float*)d_in[0];
    const float* w    = (const float*)d_in[1];
    const float* bias = (const float*)d_in[2];
    float* out = (float*)d_out;

    unsigned short* xb = (unsigned short*)d_ws;                  // 32 MiB bf16 x
    unsigned short* wb = xb + (size_t)M_ROWS * IN_F;             // 32 MiB bf16 dense W

    prep_kernel<<<16384, 256, 0, stream>>>(x, w, xb, wb);
    tri_gemm_kernel<<<N_TILES_M * N_TILES_N, 512, 0, stream>>>(xb, wb, bias, out);
}